// Round 10
// baseline (326.303 us; speedup 1.0000x reference)
//
#include <hip/hip_runtime.h>

// B=4, S=2048, D=1024, H=16, head_dim=64. Inputs fp32, output fp32.
// Round 20:
//  - gemm_qkv: MFMA switched 16x16x32 -> 32x32x16 (same pipeline/swizzle/sync;
//    16 mfma32 per k-step per wave instead of 32 mfma16; +11% rate ceiling).
//  - Wo transpose folded into attn grid (blockIdx.x==64 -> 8 transpose blocks,
//    LDS overlaid on Ks). 4 kernel launches total.
//  - GEMM pipeline = verified round-5/7: A triple-, B double-buffer, vmcnt(4).
//  - Keep: fused prologue, attn KVBLK=128 + T5 setprio + T12 in-reg softmax.
// ws (64MB): Xh[16] | Qb/ctx[16] | Kb[16] | Vt[16]  (Wo^T overlays Xh)
// d_out (32MB) pre-final scratch: Wcat[6] | mnorm[32KB] | bcat[12KB] | cnt[4]

#define Bb 4
#define Ss 2048
#define Dd 1024
#define Hh 16
#define SZt 8388608

typedef short bf16x8 __attribute__((ext_vector_type(8)));
typedef _Float16 f16x8 __attribute__((ext_vector_type(8)));
typedef float f32x4 __attribute__((ext_vector_type(4)));
typedef float f32x16 __attribute__((ext_vector_type(16)));
typedef unsigned int u32x4 __attribute__((ext_vector_type(4)));
typedef unsigned short u16;

__device__ __forceinline__ float bf2f(u16 u) {
    return __builtin_bit_cast(float, ((unsigned)u) << 16);
}
__device__ __forceinline__ u16 f2bf(float f) {
    unsigned u = __builtin_bit_cast(unsigned, f);
    unsigned r = 0x7FFFu + ((u >> 16) & 1u);
    return (u16)((u + r) >> 16);
}
__device__ __forceinline__ u16 f2h(float f) {
    _Float16 h = (_Float16)f;
    return __builtin_bit_cast(u16, h);
}
__device__ __forceinline__ bf16x8 ldfrag(const u16* p) {
    return __builtin_bit_cast(bf16x8, *(const uint4*)p);
}
__device__ __forceinline__ f16x8 ldfragh(const u16* p) {
    return __builtin_bit_cast(f16x8, *(const uint4*)p);
}
__device__ __forceinline__ f32x4 mfma16b(bf16x8 a, bf16x8 b, f32x4 c) {
    return __builtin_amdgcn_mfma_f32_16x16x32_bf16(a, b, c, 0, 0, 0);
}
__device__ __forceinline__ f32x16 mfma32(bf16x8 a, bf16x8 b, f32x16 c) {
    return __builtin_amdgcn_mfma_f32_32x32x16_bf16(a, b, c, 0, 0, 0);
}
__device__ __forceinline__ f32x16 mfma32h(f16x8 a, f16x8 b, f32x16 c) {
    return __builtin_amdgcn_mfma_f32_32x32x16_f16(a, b, c, 0, 0, 0);
}
// pack two f32 -> one u32 of 2x bf16 (lo=a, hi=b); no builtin on gfx950 (T12 recipe)
__device__ __forceinline__ unsigned cvt_pk_bf16(float a, float b) {
    unsigned r;
    asm("v_cvt_pk_bf16_f32 %0, %1, %2" : "=v"(r) : "v"(a), "v"(b));
    return r;
}
// async global->LDS, 16B/lane; LDS dest = wave-uniform base + lane*16 (m97 contract)
__device__ __forceinline__ void gl2lds16(const u16* g, u16* l) {
    __builtin_amdgcn_global_load_lds(
        (const __attribute__((address_space(1))) u16*)g,
        (__attribute__((address_space(3))) u16*)l, 16, 0, 0);
}

// ---------------- fused prologue: convert X, transpose Wq/Wk/Wv, concat bias, mask ----------------
// grid = 8192 (convert) + 3072 (3x transpose) + 12 (concat) + 1 (mask) = 11277 blocks x 256 thr
__global__ __launch_bounds__(256) void prologue(
    const float* __restrict__ X, u16* __restrict__ Xh,
    const float* __restrict__ Wq, const float* __restrict__ Wk, const float* __restrict__ Wv,
    u16* __restrict__ Wqt, u16* __restrict__ Wkt, u16* __restrict__ Wvt,
    const float* __restrict__ bq, const float* __restrict__ bk, const float* __restrict__ bv,
    float* __restrict__ bcat,
    const unsigned char* __restrict__ mraw, float* __restrict__ mnorm, float* __restrict__ cntp)
{
    __shared__ float tl[32][33];
    __shared__ int flags;
    __shared__ float scnt[Bb];
    const int blk = blockIdx.x, tid = threadIdx.x;

    if (blk < 8192) {                               // X fp32 -> fp16
        size_t i = ((size_t)blk * 256 + tid) * 4;
        float4 v = *(const float4*)(X + i);
        u16 h0 = f2h(v.x), h1 = f2h(v.y), h2 = f2h(v.z), h3 = f2h(v.w);
        uint2 ph = { (unsigned)h0 | ((unsigned)h1 << 16), (unsigned)h2 | ((unsigned)h3 << 16) };
        *(uint2*)(Xh + i) = ph;
    } else if (blk < 11264) {                       // W transpose fp32 -> fp16 (3 weights)
        int idx = blk - 8192;
        int w = idx >> 10, t = idx & 1023;
        const float* W = (w == 0) ? Wq : ((w == 1) ? Wk : Wv);
        u16* Wt = (w == 0) ? Wqt : ((w == 1) ? Wkt : Wvt);
        const int tx = tid & 31, ty = tid >> 5;     // 32 x 8
        const int n0 = (t & 31) * 32, k0 = (t >> 5) * 32;
        #pragma unroll
        for (int i = 0; i < 4; i++)
            tl[ty + i * 8][tx] = W[(size_t)(k0 + ty + i * 8) * Dd + n0 + tx];
        __syncthreads();
        #pragma unroll
        for (int i = 0; i < 4; i++)
            Wt[(size_t)(n0 + ty + i * 8) * Dd + k0 + tx] = f2h(tl[tx][ty + i * 8]);
    } else if (blk < 11276) {                       // bias concat
        int i = (blk - 11264) * 256 + tid;
        bcat[i] = (i < 1024) ? bq[i] : ((i < 2048) ? bk[i - 1024] : bv[i - 2048]);
    } else {                                        // mask normalization + per-batch count
        const int n = Bb * Ss;
        if (tid == 0) flags = 0;
        if (tid < Bb) scnt[tid] = 0.f;
        __syncthreads();
        int f = 0;
        for (int i = tid; i < n; i += 256) {
            unsigned char c = mraw[i];
            if ((i & 3) != 0 && c) f |= 1;
            if ((i & 3) == 1 && c >= 2) f |= 2;
            if ((i & 3) == 3 && c >= 2) f |= 4;
        }
        if (f) atomicOr(&flags, f);
        __syncthreads();
        int fl = flags;
        int layout;                                 // 0=int32, 1=u8, 2=bf16, 3=f32
        if (!(fl & 1)) layout = 0;
        else if (fl & 2) layout = 2;
        else if (fl & 4) layout = 3;
        else layout = 1;
        for (int i = tid; i < n; i += 256) {
            int v;
            if (layout == 0)      v = ((const int*)mraw)[i];
            else if (layout == 1) v = mraw[i];
            else if (layout == 2) v = ((const u16*)mraw)[i] != 0;
            else                  v = ((const unsigned*)mraw)[i] != 0;
            mnorm[i] = (v != 0) ? 1.0f : 0.0f;
            if (v == 0) atomicAdd(&scnt[i >> 11], 1.0f);
        }
        __syncthreads();
        if (tid < Bb) cntp[tid] = scnt[tid];
    }
}

// ---------------- fused QKV GEMM (fp16, pipelined 256x128, mfma 32x32x16) ----------------
__global__ __launch_bounds__(512, 2) void gemm_qkv(
    const u16* __restrict__ Ah, const u16* __restrict__ Wcat, const float* __restrict__ bcat,
    const float* __restrict__ mnorm,
    u16* __restrict__ Qb, u16* __restrict__ Kb, u16* __restrict__ Vt)
{
    __shared__ u16 As[3][256][64];   // 96 KiB, triple-buffered
    __shared__ u16 Bs[2][128][64];   // 32 KiB, double-buffered
    const int tid = threadIdx.x, lane = tid & 63, wave = tid >> 6;
    const int wm = wave >> 1, wn = wave & 1;
    const int bm = blockIdx.y * 256, bn = blockIdx.x * 128;
    const bool isQ = (bn < 1024);
    const int l31 = lane & 31, hi = lane >> 5;
    const int rl = lane >> 3;                       // row-in-chunk 0..7
    const int s8 = ((lane & 7) ^ rl) * 8;           // T2 pre-swizzled source slot (u16 units)
    const u16* agp = Ah + (size_t)(bm + wave * 32 + rl) * Dd + s8;
    const u16* bgp = Wcat + (size_t)(bn + wave * 16 + rl) * Dd + s8;

    f32x16 acc[2][2] = {};

    auto stageA = [&](int slot, int kt) {
        u16* d = &As[slot][wave * 32][0];           // wave-uniform dest
        const u16* g = agp + kt * 64;
        #pragma unroll
        for (int j = 0; j < 4; ++j)
            gl2lds16(g + (size_t)(j * 8) * Dd, d + j * 8 * 64);
    };
    auto stageB = [&](int slot, int kt) {
        u16* d = &Bs[slot][wave * 16][0];
        const u16* g = bgp + kt * 64;
        #pragma unroll
        for (int j = 0; j < 2; ++j)
            gl2lds16(g + (size_t)(j * 8) * Dd, d + j * 8 * 64);
    };

    // prologue: A0(4), B0(2), A1(4) -> wait until only A1 outstanding
    stageA(0, 0); stageB(0, 0); stageA(1, 1);
    asm volatile("s_waitcnt vmcnt(4)" ::: "memory");
    __builtin_amdgcn_s_barrier();

    int cs = 0;                                     // compute slot for A
    for (int t = 0; t < 16; ++t) {
        if (t < 15) stageB((t + 1) & 1, t + 1);
        if (t < 14) { int ss = (cs >= 1) ? cs - 1 : cs + 2; stageA(ss, t + 2); }
        #pragma unroll
        for (int kq = 0; kq < 4; kq++) {
            f16x8 b[2], a[2];
            #pragma unroll
            for (int nt = 0; nt < 2; nt++)
                b[nt] = ldfragh(&Bs[t & 1][wn * 64 + nt * 32 + l31][(kq * 16 + hi * 8) ^ ((l31 & 7) * 8)]);
            #pragma unroll
            for (int mt = 0; mt < 2; mt++)
                a[mt] = ldfragh(&As[cs][wm * 64 + mt * 32 + l31][(kq * 16 + hi * 8) ^ ((l31 & 7) * 8)]);
            #pragma unroll
            for (int mt = 0; mt < 2; mt++)
                #pragma unroll
                for (int nt = 0; nt < 2; nt++)
                    acc[mt][nt] = mfma32h(a[mt], b[nt], acc[mt][nt]);
        }
        // counted drain: oldest {A(t+1), B(t+1)} done; {A(t+2)} stays in flight
        if (t < 14)       asm volatile("s_waitcnt vmcnt(4)" ::: "memory");
        else if (t == 14) asm volatile("s_waitcnt vmcnt(0)" ::: "memory");
        if (t < 15) __builtin_amdgcn_s_barrier();
        cs = (cs >= 2) ? 0 : cs + 1;
    }

    // epilogue: C layout (32x32): col = bn + wn*64 + nt*32 + l31;
    // row = bm + wm*64 + mt*32 + 8*rq + 4*hi + j (reg = rq*4 + j)
    const float LOG2E = 1.44269504088896f;
    float bvv[2];
    #pragma unroll
    for (int nt = 0; nt < 2; nt++) bvv[nt] = bcat[bn + wn * 64 + nt * 32 + l31];
    #pragma unroll
    for (int mt = 0; mt < 2; mt++) {
        #pragma unroll
        for (int rq = 0; rq < 4; rq++) {
            int r0 = bm + wm * 64 + mt * 32 + 8 * rq + 4 * hi;
            float mk[4];
            if (!isQ) {
                #pragma unroll
                for (int j = 0; j < 4; j++) mk[j] = mnorm[r0 + j];
            }
            #pragma unroll
            for (int nt = 0; nt < 2; nt++) {
                int col = bn + wn * 64 + nt * 32 + l31;
                if (col < 1024) {                              // Q fp16 (pre-scaled by log2e)
                    #pragma unroll
                    for (int j = 0; j < 4; j++)
                        Qb[(size_t)(r0 + j) * Dd + col] = f2h((acc[mt][nt][rq * 4 + j] + bvv[nt]) * LOG2E);
                } else if (col < 2048) {                       // K fp16 (masked rows -> 0)
                    int c2 = col - 1024;
                    #pragma unroll
                    for (int j = 0; j < 4; j++)
                        Kb[(size_t)(r0 + j) * Dd + c2] = f2h((acc[mt][nt][rq * 4 + j] + bvv[nt]) * mk[j]);
                } else {                                       // V bf16, transposed [b][h][d][s], masked
                    int c2 = col - 2048;
                    int hh = c2 >> 6, dd = c2 & 63, b_ = r0 >> 11, s0 = r0 & 2047;
                    u16 e0 = f2bf((acc[mt][nt][rq * 4 + 0] + bvv[nt]) * mk[0]);
                    u16 e1 = f2bf((acc[mt][nt][rq * 4 + 1] + bvv[nt]) * mk[1]);
                    u16 e2 = f2bf((acc[mt][nt][rq * 4 + 2] + bvv[nt]) * mk[2]);
                    u16 e3 = f2bf((acc[mt][nt][rq * 4 + 3] + bvv[nt]) * mk[3]);
                    uint2 pk = { (unsigned)e0 | ((unsigned)e1 << 16), (unsigned)e2 | ((unsigned)e3 << 16) };
                    *(uint2*)(Vt + (size_t)((b_ * Hh + hh) * 64 + dd) * Ss + s0) = pk;
                }
            }
        }
    }
}

// ---------------- output projection (bf16, pipelined 256x128): fp32 out ----------------
__global__ __launch_bounds__(512, 2) void gemm_out(
    const u16* __restrict__ Ah, const u16* __restrict__ Wt,
    const float* __restrict__ bias, float* __restrict__ Cout)
{
    __shared__ u16 As[3][256][64];
    __shared__ u16 Bs[2][128][64];
    const int tid = threadIdx.x, lane = tid & 63, wave = tid >> 6;
    const int wm = wave >> 1, wn = wave & 1;
    const int bm = blockIdx.y * 256, bn = blockIdx.x * 128;
    const int l15 = lane & 15, lq = lane >> 4;
    const int rl = lane >> 3;
    const int s8 = ((lane & 7) ^ rl) * 8;
    const u16* agp = Ah + (size_t)(bm + wave * 32 + rl) * Dd + s8;
    const u16* bgp = Wt + (size_t)(bn + wave * 16 + rl) * Dd + s8;

    f32x4 acc[4][4] = {};

    auto stageA = [&](int slot, int kt) {
        u16* d = &As[slot][wave * 32][0];
        const u16* g = agp + kt * 64;
        #pragma unroll
        for (int j = 0; j < 4; ++j)
            gl2lds16(g + (size_t)(j * 8) * Dd, d + j * 8 * 64);
    };
    auto stageB = [&](int slot, int kt) {
        u16* d = &Bs[slot][wave * 16][0];
        const u16* g = bgp + kt * 64;
        #pragma unroll
        for (int j = 0; j < 2; ++j)
            gl2lds16(g + (size_t)(j * 8) * Dd, d + j * 8 * 64);
    };

    stageA(0, 0); stageB(0, 0); stageA(1, 1);
    asm volatile("s_waitcnt vmcnt(4)" ::: "memory");
    __builtin_amdgcn_s_barrier();

    int cs = 0;
    for (int t = 0; t < 16; ++t) {
        if (t < 15) stageB((t + 1) & 1, t + 1);
        if (t < 14) { int ss = (cs >= 1) ? cs - 1 : cs + 2; stageA(ss, t + 2); }
        #pragma unroll
        for (int kf = 0; kf < 2; kf++) {
            bf16x8 b[4], a[4];
            #pragma unroll
            for (int nt = 0; nt < 4; nt++)
                b[nt] = ldfrag(&Bs[t & 1][wn * 64 + nt * 16 + l15][(kf * 32 + lq * 8) ^ ((l15 & 7) * 8)]);
            #pragma unroll
            for (int mt = 0; mt < 4; mt++)
                a[mt] = ldfrag(&As[cs][wm * 64 + mt * 16 + l15][(kf * 32 + lq * 8) ^ ((l15 & 7) * 8)]);
            #pragma unroll
            for (int mt = 0; mt < 4; mt++)
                #pragma unroll
                for (int nt = 0; nt < 4; nt++)
                    acc[mt][nt] = mfma16b(a[mt], b[nt], acc[mt][nt]);
        }
        if (t < 14)       asm volatile("s_waitcnt vmcnt(4)" ::: "memory");
        else if (t == 14) asm volatile("s_waitcnt vmcnt(0)" ::: "memory");
        if (t < 15) __builtin_amdgcn_s_barrier();
        cs = (cs >= 2) ? 0 : cs + 1;
    }

    float bv[4];
    #pragma unroll
    for (int nt = 0; nt < 4; nt++) bv[nt] = bias[bn + wn * 64 + nt * 16 + l15];
    #pragma unroll
    for (int mt = 0; mt < 4; mt++) {
        int r0 = bm + wm * 64 + mt * 16 + lq * 4;
        #pragma unroll
        for (int nt = 0; nt < 4; nt++) {
            int col = bn + wn * 64 + nt * 16 + l15;
            #pragma unroll
            for (int rr = 0; rr < 4; rr++)
                Cout[(size_t)(r0 + rr) * Dd + col] = acc[mt][nt][rr] + bv[nt];
        }
    }
}

// ---------------- MFMA flash attention v8: KVBLK=128, T12, setprio, + fused Wo transpose --------
// grid (65, 8): x<64 -> attention (bh = x); x==64 -> Wo transpose (8 blocks, 128 tiles each).
__global__ __launch_bounds__(512, 4) void attn_mfma(
    u16* qctx, const u16* __restrict__ Kb, const u16* __restrict__ Vt,
    const float* __restrict__ maskf, const float* __restrict__ cntp,
    const float* __restrict__ Wo, u16* __restrict__ Wot)
{
    __shared__ u16 Ks[128][72];      // [key][d] fp16  (144B rows)
    __shared__ u16 Vs[64][136];      // [d][key] bf16  (272B rows)
    __shared__ float li_s[8][32];    // per-wave li broadcast (epilogue only)
    const int tid = threadIdx.x, lane = tid & 63, wave = tid >> 6;

    if (blockIdx.x == 64) {
        // ---- Wo [K][N] fp32 -> Wot [N][K] bf16; LDS overlaid on Ks (18 KB >= 2x32x33x4) ----
        float* tlb = (float*)&Ks[0][0];
        const int sub = tid >> 8;                   // 0..1 (two tiles in parallel)
        const int st = tid & 255;
        const int tx = st & 31, ty = st >> 5;       // 32 x 8
        float* tl = tlb + sub * 32 * 33;
        #pragma unroll 1
        for (int it = 0; it < 64; ++it) {
            int t = blockIdx.y * 128 + it * 2 + sub;
            int n0 = (t & 31) * 32, k0 = (t >> 5) * 32;
            #pragma unroll
            for (int i = 0; i < 4; i++)
                tl[(ty + i * 8) * 33 + tx] = Wo[(size_t)(k0 + ty + i * 8) * Dd + n0 + tx];
            __syncthreads();
            #pragma unroll
            for (int i = 0; i < 4; i++)
                Wot[(size_t)(n0 + ty + i * 8) * Dd + k0 + tx] = f2bf(tl[tx * 33 + ty + i * 8]);
            __syncthreads();
        }
        return;
    }

    const int l31 = lane & 31, hi = lane >> 5;
    const int bh = blockIdx.x, h = bh & 15, b = bh >> 4;
    const int q0 = blockIdx.y * 256;

    f16x8 qa[4];
    {
        const u16* qp = qctx + (size_t)(b * Ss + q0 + wave * 32 + l31) * Dd + h * 64 + hi * 8;
        #pragma unroll
        for (int kf = 0; kf < 4; kf++) qa[kf] = ldfragh(qp + kf * 16);
    }

    // K staging: rows kr, kr+64 (keys within tile); V staging: d rows vd, vd+32
    const int kr = tid >> 3, kc = (tid & 7) * 8;
    const int vd = tid >> 4, vc = (tid & 15) * 8;
    const u16* kgb = Kb + ((size_t)b * Ss + kr) * Dd + h * 64 + kc;
    const u16* vgb = Vt + (((size_t)(b * Hh + h)) * 64 + vd) * Ss + vc;

    f32x16 acc0 = {}, acc1 = {};
    float li = 0.f;

    uint4 kreg0 = *(const uint4*)(kgb);
    uint4 kreg1 = *(const uint4*)(kgb + (size_t)64 * Dd);
    uint4 vreg0 = *(const uint4*)(vgb);
    uint4 vreg1 = *(const uint4*)(vgb + (size_t)32 * Ss);

    for (int k0 = 0; k0 < Ss; k0 += 128) {
        __syncthreads();
        *(uint4*)&Ks[kr][kc]      = kreg0;
        *(uint4*)&Ks[kr + 64][kc] = kreg1;
        *(uint4*)&Vs[vd][vc]      = vreg0;
        *(uint4*)&Vs[vd + 32][vc] = vreg1;
        __syncthreads();
        int k0n = (k0 + 128 < Ss) ? k0 + 128 : 0;
        kreg0 = *(const uint4*)(kgb + (size_t)k0n * Dd);
        kreg1 = *(const uint4*)(kgb + (size_t)(k0n + 64) * Dd);
        vreg0 = *(const uint4*)(vgb + k0n);
        vreg1 = *(const uint4*)(vgb + (size_t)32 * Ss + k0n);

        #pragma unroll
        for (int nt = 0; nt < 4; nt++) {
            // QK^T swapped: A=K rows (32 keys), B=Q cols (32 q). Lane: q=l31, key=crow(r,hi).
            f32x16 sc = {};
            __builtin_amdgcn_s_setprio(1);
            #pragma unroll
            for (int kf = 0; kf < 4; kf++) {
                f16x8 kb = ldfragh(&Ks[nt * 32 + l31][kf * 16 + hi * 8]);
                sc = mfma32h(kb, qa[kf], sc);
            }
            __builtin_amdgcn_s_setprio(0);
            float p[16];
            #pragma unroll
            for (int r = 0; r < 8; r++) p[r] = __builtin_amdgcn_exp2f(sc[r]);
            li += ((p[0] + p[1]) + (p[2] + p[3])) + ((p[4] + p[5]) + (p[6] + p[7]));
            {
                unsigned w0 = cvt_pk_bf16(p[0], p[1]), w1 = cvt_pk_bf16(p[2], p[3]);
                unsigned w2 = cvt_pk_bf16(p[4], p[5]), w3 = cvt_pk_bf16(p[6], p[7]);
                auto s02 = __builtin_amdgcn_permlane32_swap((int)w0, (int)w2, false, false);
                auto s13 = __builtin_amdgcn_permlane32_swap((int)w1, (int)w3, false, false);
                u32x4 pw = { (unsigned)s02[0], (unsigned)s13[0], (unsigned)s02[1], (unsigned)s13[1] };
                bf16x8 pa0 = __builtin_bit_cast(bf16x8, pw);
                bf16x8 v00 = ldfrag(&Vs[l31][nt * 32 + hi * 8]);
                bf16x8 v10 = ldfrag(&Vs[32 + l31][nt * 32 + hi * 8]);
                __builtin_amdgcn_s_setprio(1);
                acc0 = mfma32(pa0, v00, acc0);
                acc1 = mfma32(pa0, v10, acc1);
                __builtin_amdgcn_s_setprio(0);
            }
            #pragma unroll
            for (int r = 8; r < 16; r++) p[r] = __builtin_amdgcn_exp2f(sc[r]);
            li += ((p[8] + p[9]) + (p[10] + p[11])) + ((p[12] + p[13]) + (p[14] + p[15]));
            {
                unsigned w4 = cvt_pk_bf16(p[8], p[9]),  w5 = cvt_pk_bf16(p[10], p[11]);
                unsigned w6 = cvt_pk_bf16(p[12], p[13]), w7 = cvt_pk_bf16(p[14], p[15]);
                auto s46 = __builtin_amdgcn_permlane32_swap((int)w4, (int)w6, false, false);
                auto s57 = __builtin_amdgcn_permlane32_swap((int)w5, (int)w7, false, false);
                u32x4 pw = { (unsigned)s46[0], (unsigned)s57[0], (unsigned)s46[1], (unsigned)s57[1] };
                bf16x8 pa1 = __builtin_bit_cast(bf16x8, pw);
                bf16x8 v01 = ldfrag(&Vs[l31][nt * 32 + 16 + hi * 8]);
                bf16x8 v11 = ldfrag(&Vs[32 + l31][nt * 32 + 16 + hi * 8]);
                __builtin_amdgcn_s_setprio(1);
                acc0 = mfma32(pa1, v01, acc0);
                acc1 = mfma32(pa1, v11, acc1);
                __builtin_amdgcn_s_setprio(0);
            }
        }
    }

    float li_tot = li + __shfl_xor(li, 32);
    if (hi == 0) li_s[wave][l31] = li_tot;
    __builtin_amdgcn_s_barrier();
    float cntb = cntp[b];
    #pragma unroll
    for (int g = 0; g < 4; g++) {
        float4 lv = *(const float4*)&li_s[wave][g * 8 + hi * 4];
        #pragma unroll
        for (int j = 0; j < 4; j++) {
            int r = g * 4 + j;
            int row = j + 8 * g + 4 * hi;
            int q = q0 + wave * 32 + row;
            float qm = maskf[b * Ss + q];
            float den = lv[j] - cntb;
            float rl = den > 0.f ? qm / den : 0.f;
            u16* op = qctx + (size_t)(b * Ss + q) * Dd + h * 64 + l31;
            op[0]  = f2bf(acc0[r] * rl);
            op[32] = f2bf(acc1[r] * rl);
        }
    }
}

extern "C" void kernel_launch(void* const* d_in, const int* in_sizes, int n_in,
                              void* d_out, int out_size, void* d_ws, size_t ws_size,
                              hipStream_t stream) {
    const float* X  = (const float*)d_in[0];
    const unsigned char* mr = (const unsigned char*)d_in[1];
    const float* Wq = (const float*)d_in[2];
    const float* bq = (const float*)d_in[3];
    const float* Wk = (const float*)d_in[4];
    const float* bk = (const float*)d_in[5];
    const float* Wv = (const float*)d_in[6];
    const float* bv = (const float*)d_in[7];
    const float* Wo = (const float*)d_in[8];
    const float* bo = (const float*)d_in[9];
    float* out = (float*)d_out;

    // ws (64 MB)
    u16* wsb = (u16*)d_ws;
    u16* Xh  = wsb;                // fp16 X; dies after QKV-gemm; Wo^T overlays
    u16* Qb  = wsb + (size_t)SZt;  // fp16 Q; ctx (bf16) aliases after attention
    u16* Kb  = wsb + 2 * (size_t)SZt;   // fp16 K
    u16* Vt  = wsb + 3 * (size_t)SZt;   // bf16 V^T
    u16* Wot = Xh;
    // d_out scratch (all dead before gemm_out writes d_out)
    u16* ob  = (u16*)d_out;
    u16* Wcat = ob + (size_t)SZt;              // fp16 Wqt|Wkt|Wvt contiguous = [3072][1024]
    u16* Wqt = Wcat;
    u16* Wkt = Wqt + 1048576;
    u16* Wvt = Wkt + 1048576;
    float* mnorm = (float*)(Wvt + 1048576);    // 32 KB
    float* bcat  = mnorm + Bb * Ss;            // 12 KB
    float* cntp  = bcat + 3072;                // 16 B (per-batch masked-key count)

    prologue<<<11277, 256, 0, stream>>>(X, Xh, Wq, Wk, Wv, Wqt, Wkt, Wvt,
                                        bq, bk, bv, bcat, mr, mnorm, cntp);
    gemm_qkv<<<dim3(24, 32), 512, 0, stream>>>(Xh, Wcat, bcat, mnorm, Qb, Kb, Vt);
    attn_mfma<<<dim3(Bb * Hh + 1, Ss / 256), 512, 0, stream>>>(Qb, Kb, Vt, mnorm, cntp, Wo, Wot);
    gemm_out<<<dim3(8, 32), 512, 0, stream>>>(Qb, Wot, bo, out);
}

// Round 11
// 309.707 us; speedup vs baseline: 1.0536x; 1.0536x over previous
//
#include <hip/hip_runtime.h>

// B=4, S=2048, D=1024, H=16, head_dim=64. Inputs fp32, output fp32.
// Round 21:
//  - FIX round-20 regression: attn grid x=65 broke XCD round-robin alignment
//    (same-head q-tile blocks scattered across XCDs -> K/V FETCH 27.8->149.7MB).
//    Now grid x=72 (multiple of 8): x<64 attn, x>=64 -> 64 Wo-transpose blocks
//    (16 tiles each). Same-head blocks stay on one XCD; launch fusion kept.
//  - gemm_qkv mfma 32x32x16 kept (confounded in r20; isolated this round).
//  - GEMM pipeline = verified round-5/7: A triple-, B double-buffer, vmcnt(4).
// ws (64MB): Xh[16] | Qb/ctx[16] | Kb[16] | Vt[16]  (Wo^T overlays Xh)
// d_out (32MB) pre-final scratch: Wcat[6] | mnorm[32KB] | bcat[12KB] | cnt[4]

#define Bb 4
#define Ss 2048
#define Dd 1024
#define Hh 16
#define SZt 8388608

typedef short bf16x8 __attribute__((ext_vector_type(8)));
typedef _Float16 f16x8 __attribute__((ext_vector_type(8)));
typedef float f32x4 __attribute__((ext_vector_type(4)));
typedef float f32x16 __attribute__((ext_vector_type(16)));
typedef unsigned int u32x4 __attribute__((ext_vector_type(4)));
typedef unsigned short u16;

__device__ __forceinline__ float bf2f(u16 u) {
    return __builtin_bit_cast(float, ((unsigned)u) << 16);
}
__device__ __forceinline__ u16 f2bf(float f) {
    unsigned u = __builtin_bit_cast(unsigned, f);
    unsigned r = 0x7FFFu + ((u >> 16) & 1u);
    return (u16)((u + r) >> 16);
}
__device__ __forceinline__ u16 f2h(float f) {
    _Float16 h = (_Float16)f;
    return __builtin_bit_cast(u16, h);
}
__device__ __forceinline__ bf16x8 ldfrag(const u16* p) {
    return __builtin_bit_cast(bf16x8, *(const uint4*)p);
}
__device__ __forceinline__ f16x8 ldfragh(const u16* p) {
    return __builtin_bit_cast(f16x8, *(const uint4*)p);
}
__device__ __forceinline__ f32x4 mfma16b(bf16x8 a, bf16x8 b, f32x4 c) {
    return __builtin_amdgcn_mfma_f32_16x16x32_bf16(a, b, c, 0, 0, 0);
}
__device__ __forceinline__ f32x16 mfma32(bf16x8 a, bf16x8 b, f32x16 c) {
    return __builtin_amdgcn_mfma_f32_32x32x16_bf16(a, b, c, 0, 0, 0);
}
__device__ __forceinline__ f32x16 mfma32h(f16x8 a, f16x8 b, f32x16 c) {
    return __builtin_amdgcn_mfma_f32_32x32x16_f16(a, b, c, 0, 0, 0);
}
// pack two f32 -> one u32 of 2x bf16 (lo=a, hi=b); no builtin on gfx950 (T12 recipe)
__device__ __forceinline__ unsigned cvt_pk_bf16(float a, float b) {
    unsigned r;
    asm("v_cvt_pk_bf16_f32 %0, %1, %2" : "=v"(r) : "v"(a), "v"(b));
    return r;
}
// async global->LDS, 16B/lane; LDS dest = wave-uniform base + lane*16 (m97 contract)
__device__ __forceinline__ void gl2lds16(const u16* g, u16* l) {
    __builtin_amdgcn_global_load_lds(
        (const __attribute__((address_space(1))) u16*)g,
        (__attribute__((address_space(3))) u16*)l, 16, 0, 0);
}

// ---------------- fused prologue: convert X, transpose Wq/Wk/Wv, concat bias, mask ----------------
// grid = 8192 (convert) + 3072 (3x transpose) + 12 (concat) + 1 (mask) = 11277 blocks x 256 thr
__global__ __launch_bounds__(256) void prologue(
    const float* __restrict__ X, u16* __restrict__ Xh,
    const float* __restrict__ Wq, const float* __restrict__ Wk, const float* __restrict__ Wv,
    u16* __restrict__ Wqt, u16* __restrict__ Wkt, u16* __restrict__ Wvt,
    const float* __restrict__ bq, const float* __restrict__ bk, const float* __restrict__ bv,
    float* __restrict__ bcat,
    const unsigned char* __restrict__ mraw, float* __restrict__ mnorm, float* __restrict__ cntp)
{
    __shared__ float tl[32][33];
    __shared__ int flags;
    __shared__ float scnt[Bb];
    const int blk = blockIdx.x, tid = threadIdx.x;

    if (blk < 8192) {                               // X fp32 -> fp16
        size_t i = ((size_t)blk * 256 + tid) * 4;
        float4 v = *(const float4*)(X + i);
        u16 h0 = f2h(v.x), h1 = f2h(v.y), h2 = f2h(v.z), h3 = f2h(v.w);
        uint2 ph = { (unsigned)h0 | ((unsigned)h1 << 16), (unsigned)h2 | ((unsigned)h3 << 16) };
        *(uint2*)(Xh + i) = ph;
    } else if (blk < 11264) {                       // W transpose fp32 -> fp16 (3 weights)
        int idx = blk - 8192;
        int w = idx >> 10, t = idx & 1023;
        const float* W = (w == 0) ? Wq : ((w == 1) ? Wk : Wv);
        u16* Wt = (w == 0) ? Wqt : ((w == 1) ? Wkt : Wvt);
        const int tx = tid & 31, ty = tid >> 5;     // 32 x 8
        const int n0 = (t & 31) * 32, k0 = (t >> 5) * 32;
        #pragma unroll
        for (int i = 0; i < 4; i++)
            tl[ty + i * 8][tx] = W[(size_t)(k0 + ty + i * 8) * Dd + n0 + tx];
        __syncthreads();
        #pragma unroll
        for (int i = 0; i < 4; i++)
            Wt[(size_t)(n0 + ty + i * 8) * Dd + k0 + tx] = f2h(tl[tx][ty + i * 8]);
    } else if (blk < 11276) {                       // bias concat
        int i = (blk - 11264) * 256 + tid;
        bcat[i] = (i < 1024) ? bq[i] : ((i < 2048) ? bk[i - 1024] : bv[i - 2048]);
    } else {                                        // mask normalization + per-batch count
        const int n = Bb * Ss;
        if (tid == 0) flags = 0;
        if (tid < Bb) scnt[tid] = 0.f;
        __syncthreads();
        int f = 0;
        for (int i = tid; i < n; i += 256) {
            unsigned char c = mraw[i];
            if ((i & 3) != 0 && c) f |= 1;
            if ((i & 3) == 1 && c >= 2) f |= 2;
            if ((i & 3) == 3 && c >= 2) f |= 4;
        }
        if (f) atomicOr(&flags, f);
        __syncthreads();
        int fl = flags;
        int layout;                                 // 0=int32, 1=u8, 2=bf16, 3=f32
        if (!(fl & 1)) layout = 0;
        else if (fl & 2) layout = 2;
        else if (fl & 4) layout = 3;
        else layout = 1;
        for (int i = tid; i < n; i += 256) {
            int v;
            if (layout == 0)      v = ((const int*)mraw)[i];
            else if (layout == 1) v = mraw[i];
            else if (layout == 2) v = ((const u16*)mraw)[i] != 0;
            else                  v = ((const unsigned*)mraw)[i] != 0;
            mnorm[i] = (v != 0) ? 1.0f : 0.0f;
            if (v == 0) atomicAdd(&scnt[i >> 11], 1.0f);
        }
        __syncthreads();
        if (tid < Bb) cntp[tid] = scnt[tid];
    }
}

// ---------------- fused QKV GEMM (fp16, pipelined 256x128, mfma 32x32x16) ----------------
__global__ __launch_bounds__(512, 2) void gemm_qkv(
    const u16* __restrict__ Ah, const u16* __restrict__ Wcat, const float* __restrict__ bcat,
    const float* __restrict__ mnorm,
    u16* __restrict__ Qb, u16* __restrict__ Kb, u16* __restrict__ Vt)
{
    __shared__ u16 As[3][256][64];   // 96 KiB, triple-buffered
    __shared__ u16 Bs[2][128][64];   // 32 KiB, double-buffered
    const int tid = threadIdx.x, lane = tid & 63, wave = tid >> 6;
    const int wm = wave >> 1, wn = wave & 1;
    const int bm = blockIdx.y * 256, bn = blockIdx.x * 128;
    const bool isQ = (bn < 1024);
    const int l31 = lane & 31, hi = lane >> 5;
    const int rl = lane >> 3;                       // row-in-chunk 0..7
    const int s8 = ((lane & 7) ^ rl) * 8;           // T2 pre-swizzled source slot (u16 units)
    const u16* agp = Ah + (size_t)(bm + wave * 32 + rl) * Dd + s8;
    const u16* bgp = Wcat + (size_t)(bn + wave * 16 + rl) * Dd + s8;

    f32x16 acc[2][2] = {};

    auto stageA = [&](int slot, int kt) {
        u16* d = &As[slot][wave * 32][0];           // wave-uniform dest
        const u16* g = agp + kt * 64;
        #pragma unroll
        for (int j = 0; j < 4; ++j)
            gl2lds16(g + (size_t)(j * 8) * Dd, d + j * 8 * 64);
    };
    auto stageB = [&](int slot, int kt) {
        u16* d = &Bs[slot][wave * 16][0];
        const u16* g = bgp + kt * 64;
        #pragma unroll
        for (int j = 0; j < 2; ++j)
            gl2lds16(g + (size_t)(j * 8) * Dd, d + j * 8 * 64);
    };

    // prologue: A0(4), B0(2), A1(4) -> wait until only A1 outstanding
    stageA(0, 0); stageB(0, 0); stageA(1, 1);
    asm volatile("s_waitcnt vmcnt(4)" ::: "memory");
    __builtin_amdgcn_s_barrier();

    int cs = 0;                                     // compute slot for A
    for (int t = 0; t < 16; ++t) {
        if (t < 15) stageB((t + 1) & 1, t + 1);
        if (t < 14) { int ss = (cs >= 1) ? cs - 1 : cs + 2; stageA(ss, t + 2); }
        #pragma unroll
        for (int kq = 0; kq < 4; kq++) {
            f16x8 b[2], a[2];
            #pragma unroll
            for (int nt = 0; nt < 2; nt++)
                b[nt] = ldfragh(&Bs[t & 1][wn * 64 + nt * 32 + l31][(kq * 16 + hi * 8) ^ ((l31 & 7) * 8)]);
            #pragma unroll
            for (int mt = 0; mt < 2; mt++)
                a[mt] = ldfragh(&As[cs][wm * 64 + mt * 32 + l31][(kq * 16 + hi * 8) ^ ((l31 & 7) * 8)]);
            #pragma unroll
            for (int mt = 0; mt < 2; mt++)
                #pragma unroll
                for (int nt = 0; nt < 2; nt++)
                    acc[mt][nt] = mfma32h(a[mt], b[nt], acc[mt][nt]);
        }
        // counted drain: oldest {A(t+1), B(t+1)} done; {A(t+2)} stays in flight
        if (t < 14)       asm volatile("s_waitcnt vmcnt(4)" ::: "memory");
        else if (t == 14) asm volatile("s_waitcnt vmcnt(0)" ::: "memory");
        if (t < 15) __builtin_amdgcn_s_barrier();
        cs = (cs >= 2) ? 0 : cs + 1;
    }

    // epilogue: C layout (32x32): col = bn + wn*64 + nt*32 + l31;
    // row = bm + wm*64 + mt*32 + 8*rq + 4*hi + j (reg = rq*4 + j)
    const float LOG2E = 1.44269504088896f;
    float bvv[2];
    #pragma unroll
    for (int nt = 0; nt < 2; nt++) bvv[nt] = bcat[bn + wn * 64 + nt * 32 + l31];
    #pragma unroll
    for (int mt = 0; mt < 2; mt++) {
        #pragma unroll
        for (int rq = 0; rq < 4; rq++) {
            int r0 = bm + wm * 64 + mt * 32 + 8 * rq + 4 * hi;
            float mk[4];
            if (!isQ) {
                #pragma unroll
                for (int j = 0; j < 4; j++) mk[j] = mnorm[r0 + j];
            }
            #pragma unroll
            for (int nt = 0; nt < 2; nt++) {
                int col = bn + wn * 64 + nt * 32 + l31;
                if (col < 1024) {                              // Q fp16 (pre-scaled by log2e)
                    #pragma unroll
                    for (int j = 0; j < 4; j++)
                        Qb[(size_t)(r0 + j) * Dd + col] = f2h((acc[mt][nt][rq * 4 + j] + bvv[nt]) * LOG2E);
                } else if (col < 2048) {                       // K fp16 (masked rows -> 0)
                    int c2 = col - 1024;
                    #pragma unroll
                    for (int j = 0; j < 4; j++)
                        Kb[(size_t)(r0 + j) * Dd + c2] = f2h((acc[mt][nt][rq * 4 + j] + bvv[nt]) * mk[j]);
                } else {                                       // V bf16, transposed [b][h][d][s], masked
                    int c2 = col - 2048;
                    int hh = c2 >> 6, dd = c2 & 63, b_ = r0 >> 11, s0 = r0 & 2047;
                    u16 e0 = f2bf((acc[mt][nt][rq * 4 + 0] + bvv[nt]) * mk[0]);
                    u16 e1 = f2bf((acc[mt][nt][rq * 4 + 1] + bvv[nt]) * mk[1]);
                    u16 e2 = f2bf((acc[mt][nt][rq * 4 + 2] + bvv[nt]) * mk[2]);
                    u16 e3 = f2bf((acc[mt][nt][rq * 4 + 3] + bvv[nt]) * mk[3]);
                    uint2 pk = { (unsigned)e0 | ((unsigned)e1 << 16), (unsigned)e2 | ((unsigned)e3 << 16) };
                    *(uint2*)(Vt + (size_t)((b_ * Hh + hh) * 64 + dd) * Ss + s0) = pk;
                }
            }
        }
    }
}

// ---------------- output projection (bf16, pipelined 256x128): fp32 out ----------------
__global__ __launch_bounds__(512, 2) void gemm_out(
    const u16* __restrict__ Ah, const u16* __restrict__ Wt,
    const float* __restrict__ bias, float* __restrict__ Cout)
{
    __shared__ u16 As[3][256][64];
    __shared__ u16 Bs[2][128][64];
    const int tid = threadIdx.x, lane = tid & 63, wave = tid >> 6;
    const int wm = wave >> 1, wn = wave & 1;
    const int bm = blockIdx.y * 256, bn = blockIdx.x * 128;
    const int l15 = lane & 15, lq = lane >> 4;
    const int rl = lane >> 3;
    const int s8 = ((lane & 7) ^ rl) * 8;
    const u16* agp = Ah + (size_t)(bm + wave * 32 + rl) * Dd + s8;
    const u16* bgp = Wt + (size_t)(bn + wave * 16 + rl) * Dd + s8;

    f32x4 acc[4][4] = {};

    auto stageA = [&](int slot, int kt) {
        u16* d = &As[slot][wave * 32][0];
        const u16* g = agp + kt * 64;
        #pragma unroll
        for (int j = 0; j < 4; ++j)
            gl2lds16(g + (size_t)(j * 8) * Dd, d + j * 8 * 64);
    };
    auto stageB = [&](int slot, int kt) {
        u16* d = &Bs[slot][wave * 16][0];
        const u16* g = bgp + kt * 64;
        #pragma unroll
        for (int j = 0; j < 2; ++j)
            gl2lds16(g + (size_t)(j * 8) * Dd, d + j * 8 * 64);
    };

    stageA(0, 0); stageB(0, 0); stageA(1, 1);
    asm volatile("s_waitcnt vmcnt(4)" ::: "memory");
    __builtin_amdgcn_s_barrier();

    int cs = 0;
    for (int t = 0; t < 16; ++t) {
        if (t < 15) stageB((t + 1) & 1, t + 1);
        if (t < 14) { int ss = (cs >= 1) ? cs - 1 : cs + 2; stageA(ss, t + 2); }
        #pragma unroll
        for (int kf = 0; kf < 2; kf++) {
            bf16x8 b[4], a[4];
            #pragma unroll
            for (int nt = 0; nt < 4; nt++)
                b[nt] = ldfrag(&Bs[t & 1][wn * 64 + nt * 16 + l15][(kf * 32 + lq * 8) ^ ((l15 & 7) * 8)]);
            #pragma unroll
            for (int mt = 0; mt < 4; mt++)
                a[mt] = ldfrag(&As[cs][wm * 64 + mt * 16 + l15][(kf * 32 + lq * 8) ^ ((l15 & 7) * 8)]);
            #pragma unroll
            for (int mt = 0; mt < 4; mt++)
                #pragma unroll
                for (int nt = 0; nt < 4; nt++)
                    acc[mt][nt] = mfma16b(a[mt], b[nt], acc[mt][nt]);
        }
        if (t < 14)       asm volatile("s_waitcnt vmcnt(4)" ::: "memory");
        else if (t == 14) asm volatile("s_waitcnt vmcnt(0)" ::: "memory");
        if (t < 15) __builtin_amdgcn_s_barrier();
        cs = (cs >= 2) ? 0 : cs + 1;
    }

    float bv[4];
    #pragma unroll
    for (int nt = 0; nt < 4; nt++) bv[nt] = bias[bn + wn * 64 + nt * 16 + l15];
    #pragma unroll
    for (int mt = 0; mt < 4; mt++) {
        int r0 = bm + wm * 64 + mt * 16 + lq * 4;
        #pragma unroll
        for (int nt = 0; nt < 4; nt++) {
            int col = bn + wn * 64 + nt * 16 + l15;
            #pragma unroll
            for (int rr = 0; rr < 4; rr++)
                Cout[(size_t)(r0 + rr) * Dd + col] = acc[mt][nt][rr] + bv[nt];
        }
    }
}

// ---------------- MFMA flash attention v8b: KVBLK=128, T12, setprio, + fused Wo transpose -------
// grid (72, 8): x<64 -> attention (bh = x); x>=64 -> Wo transpose (64 blocks, 16 tiles each).
// 72 % 8 == 0 keeps same-head q-tile blocks on one XCD (K/V L2 locality — r20 lesson).
__global__ __launch_bounds__(512, 4) void attn_mfma(
    u16* qctx, const u16* __restrict__ Kb, const u16* __restrict__ Vt,
    const float* __restrict__ maskf, const float* __restrict__ cntp,
    const float* __restrict__ Wo, u16* __restrict__ Wot)
{
    __shared__ u16 Ks[128][72];      // [key][d] fp16  (144B rows)
    __shared__ u16 Vs[64][136];      // [d][key] bf16  (272B rows)
    __shared__ float li_s[8][32];    // per-wave li broadcast (epilogue only)
    const int tid = threadIdx.x, lane = tid & 63, wave = tid >> 6;

    if (blockIdx.x >= 64) {
        // ---- Wo [K][N] fp32 -> Wot [N][K] bf16; LDS overlaid on Ks (>= 2x32x33x4 B) ----
        float* tlb = (float*)&Ks[0][0];
        const int idx = (blockIdx.x - 64) * 8 + blockIdx.y;   // 0..63
        const int sub = tid >> 8;                   // 0..1 (two tiles in parallel)
        const int st = tid & 255;
        const int tx = st & 31, ty = st >> 5;       // 32 x 8
        float* tl = tlb + sub * 32 * 33;
        #pragma unroll 1
        for (int it = 0; it < 8; ++it) {
            int t = idx * 16 + it * 2 + sub;
            int n0 = (t & 31) * 32, k0 = (t >> 5) * 32;
            #pragma unroll
            for (int i = 0; i < 4; i++)
                tl[(ty + i * 8) * 33 + tx] = Wo[(size_t)(k0 + ty + i * 8) * Dd + n0 + tx];
            __syncthreads();
            #pragma unroll
            for (int i = 0; i < 4; i++)
                Wot[(size_t)(n0 + ty + i * 8) * Dd + k0 + tx] = f2bf(tl[tx * 33 + ty + i * 8]);
            __syncthreads();
        }
        return;
    }

    const int l31 = lane & 31, hi = lane >> 5;
    const int bh = blockIdx.x, h = bh & 15, b = bh >> 4;
    const int q0 = blockIdx.y * 256;

    f16x8 qa[4];
    {
        const u16* qp = qctx + (size_t)(b * Ss + q0 + wave * 32 + l31) * Dd + h * 64 + hi * 8;
        #pragma unroll
        for (int kf = 0; kf < 4; kf++) qa[kf] = ldfragh(qp + kf * 16);
    }

    // K staging: rows kr, kr+64 (keys within tile); V staging: d rows vd, vd+32
    const int kr = tid >> 3, kc = (tid & 7) * 8;
    const int vd = tid >> 4, vc = (tid & 15) * 8;
    const u16* kgb = Kb + ((size_t)b * Ss + kr) * Dd + h * 64 + kc;
    const u16* vgb = Vt + (((size_t)(b * Hh + h)) * 64 + vd) * Ss + vc;

    f32x16 acc0 = {}, acc1 = {};
    float li = 0.f;

    uint4 kreg0 = *(const uint4*)(kgb);
    uint4 kreg1 = *(const uint4*)(kgb + (size_t)64 * Dd);
    uint4 vreg0 = *(const uint4*)(vgb);
    uint4 vreg1 = *(const uint4*)(vgb + (size_t)32 * Ss);

    for (int k0 = 0; k0 < Ss; k0 += 128) {
        __syncthreads();
        *(uint4*)&Ks[kr][kc]      = kreg0;
        *(uint4*)&Ks[kr + 64][kc] = kreg1;
        *(uint4*)&Vs[vd][vc]      = vreg0;
        *(uint4*)&Vs[vd + 32][vc] = vreg1;
        __syncthreads();
        int k0n = (k0 + 128 < Ss) ? k0 + 128 : 0;
        kreg0 = *(const uint4*)(kgb + (size_t)k0n * Dd);
        kreg1 = *(const uint4*)(kgb + (size_t)(k0n + 64) * Dd);
        vreg0 = *(const uint4*)(vgb + k0n);
        vreg1 = *(const uint4*)(vgb + (size_t)32 * Ss + k0n);

        #pragma unroll
        for (int nt = 0; nt < 4; nt++) {
            // QK^T swapped: A=K rows (32 keys), B=Q cols (32 q). Lane: q=l31, key=crow(r,hi).
            f32x16 sc = {};
            __builtin_amdgcn_s_setprio(1);
            #pragma unroll
            for (int kf = 0; kf < 4; kf++) {
                f16x8 kb = ldfragh(&Ks[nt * 32 + l31][kf * 16 + hi * 8]);
                sc = mfma32h(kb, qa[kf], sc);
            }
            __builtin_amdgcn_s_setprio(0);
            float p[16];
            #pragma unroll
            for (int r = 0; r < 8; r++) p[r] = __builtin_amdgcn_exp2f(sc[r]);
            li += ((p[0] + p[1]) + (p[2] + p[3])) + ((p[4] + p[5]) + (p[6] + p[7]));
            {
                unsigned w0 = cvt_pk_bf16(p[0], p[1]), w1 = cvt_pk_bf16(p[2], p[3]);
                unsigned w2 = cvt_pk_bf16(p[4], p[5]), w3 = cvt_pk_bf16(p[6], p[7]);
                auto s02 = __builtin_amdgcn_permlane32_swap((int)w0, (int)w2, false, false);
                auto s13 = __builtin_amdgcn_permlane32_swap((int)w1, (int)w3, false, false);
                u32x4 pw = { (unsigned)s02[0], (unsigned)s13[0], (unsigned)s02[1], (unsigned)s13[1] };
                bf16x8 pa0 = __builtin_bit_cast(bf16x8, pw);
                bf16x8 v00 = ldfrag(&Vs[l31][nt * 32 + hi * 8]);
                bf16x8 v10 = ldfrag(&Vs[32 + l31][nt * 32 + hi * 8]);
                __builtin_amdgcn_s_setprio(1);
                acc0 = mfma32(pa0, v00, acc0);
                acc1 = mfma32(pa0, v10, acc1);
                __builtin_amdgcn_s_setprio(0);
            }
            #pragma unroll
            for (int r = 8; r < 16; r++) p[r] = __builtin_amdgcn_exp2f(sc[r]);
            li += ((p[8] + p[9]) + (p[10] + p[11])) + ((p[12] + p[13]) + (p[14] + p[15]));
            {
                unsigned w4 = cvt_pk_bf16(p[8], p[9]),  w5 = cvt_pk_bf16(p[10], p[11]);
                unsigned w6 = cvt_pk_bf16(p[12], p[13]), w7 = cvt_pk_bf16(p[14], p[15]);
                auto s46 = __builtin_amdgcn_permlane32_swap((int)w4, (int)w6, false, false);
                auto s57 = __builtin_amdgcn_permlane32_swap((int)w5, (int)w7, false, false);
                u32x4 pw = { (unsigned)s46[0], (unsigned)s57[0], (unsigned)s46[1], (unsigned)s57[1] };
                bf16x8 pa1 = __builtin_bit_cast(bf16x8, pw);
                bf16x8 v01 = ldfrag(&Vs[l31][nt * 32 + 16 + hi * 8]);
                bf16x8 v11 = ldfrag(&Vs[32 + l31][nt * 32 + 16 + hi * 8]);
                __builtin_amdgcn_s_setprio(1);
                acc0 = mfma32(pa1, v01, acc0);
                acc1 = mfma32(pa1, v11, acc1);
                __builtin_amdgcn_s_setprio(0);
            }
        }
    }

    float li_tot = li + __shfl_xor(li, 32);
    if (hi == 0) li_s[wave][l31] = li_tot;
    __builtin_amdgcn_s_barrier();
    float cntb = cntp[b];
    #pragma unroll
    for (int g = 0; g < 4; g++) {
        float4 lv = *(const float4*)&li_s[wave][g * 8 + hi * 4];
        #pragma unroll
        for (int j = 0; j < 4; j++) {
            int r = g * 4 + j;
            int row = j + 8 * g + 4 * hi;
            int q = q0 + wave * 32 + row;
            float qm = maskf[b * Ss + q];
            float den = lv[j] - cntb;
            float rl = den > 0.f ? qm / den : 0.f;
            u16* op = qctx + (size_t)(b * Ss + q) * Dd + h * 64 + l31;
            op[0]  = f2bf(acc0[r] * rl);
            op[32] = f2bf(acc1[r] * rl);
        }
    }
}

extern "C" void kernel_launch(void* const* d_in, const int* in_sizes, int n_in,
                              void* d_out, int out_size, void* d_ws, size_t ws_size,
                              hipStream_t stream) {
    const float* X  = (const float*)d_in[0];
    const unsigned char* mr = (const unsigned char*)d_in[1];
    const float* Wq = (const float*)d_in[2];
    const float* bq = (const float*)d_in[3];
    const float* Wk = (const float*)d_in[4];
    const float* bk = (const float*)d_in[5];
    const float* Wv = (const float*)d_in[6];
    const float* bv = (const float*)d_in[7];
    const float* Wo = (const float*)d_in[8];
    const float* bo = (const float*)d_in[9];
    float* out = (float*)d_out;

    // ws (64 MB)
    u16* wsb = (u16*)d_ws;
    u16* Xh  = wsb;                // fp16 X; dies after QKV-gemm; Wo^T overlays
    u16* Qb  = wsb + (size_t)SZt;  // fp16 Q; ctx (bf16) aliases after attention
    u16* Kb  = wsb + 2 * (size_t)SZt;   // fp16 K
    u16* Vt  = wsb + 3 * (size_t)SZt;   // bf16 V^T
    u16* Wot = Xh;
    // d_out scratch (all dead before gemm_out writes d_out)
    u16* ob  = (u16*)d_out;
    u16* Wcat = ob + (size_t)SZt;              // fp16 Wqt|Wkt|Wvt contiguous = [3072][1024]
    u16* Wqt = Wcat;
    u16* Wkt = Wqt + 1048576;
    u16* Wvt = Wkt + 1048576;
    float* mnorm = (float*)(Wvt + 1048576);    // 32 KB
    float* bcat  = mnorm + Bb * Ss;            // 12 KB
    float* cntp  = bcat + 3072;                // 16 B (per-batch masked-key count)

    prologue<<<11277, 256, 0, stream>>>(X, Xh, Wq, Wk, Wv, Wqt, Wkt, Wvt,
                                        bq, bk, bv, bcat, mr, mnorm, cntp);
    gemm_qkv<<<dim3(24, 32), 512, 0, stream>>>(Xh, Wcat, bcat, mnorm, Qb, Kb, Vt);
    attn_mfma<<<dim3(72, Ss / 256), 512, 0, stream>>>(Qb, Kb, Vt, mnorm, cntp, Wo, Wot);
    gemm_out<<<dim3(8, 32), 512, 0, stream>>>(Qb, Wot, bo, out);
}

// Round 14
// 294.519 us; speedup vs baseline: 1.1079x; 1.0516x over previous
//
#include <hip/hip_runtime.h>

// B=4, S=2048, D=1024, H=16, head_dim=64. Inputs fp32, output fp32.
// Round 24 = round 22/23 resubmit (broker failed twice; kernel never ran; audited clean).
//  - REVERT gemm_qkv mfma 32x32x16 -> 16x16x32 (r11 isolated: 6.29M bank conflicts,
//    +2.4us; the 32-row stride-128B read is ~8-way bank-aliased, 16x16 pattern is 0).
//  - prologue block reorder: mask block is now blk 0 (was last -> ~10us straggler
//    tail after the convert wave). mask=0, bias=1..12, transpose=13..3084,
//    convert=3085..11276.
//  - Keep: attn v8b grid 72 (x>=64 = fused Wo transpose; 72%8==0 preserves XCD
//    K/V locality — r20/r21 lesson), KVBLK=128, T5 setprio, T12 in-reg softmax.
//  - GEMM pipeline = verified round-5/7: A triple-, B double-buffer, vmcnt(4).
// ws (64MB): Xh[16] | Qb/ctx[16] | Kb[16] | Vt[16]  (Wo^T overlays Xh)
// d_out (32MB) pre-final scratch: Wcat[6] | mnorm[32KB] | bcat[12KB] | cnt[4]

#define Bb 4
#define Ss 2048
#define Dd 1024
#define Hh 16
#define SZt 8388608

typedef short bf16x8 __attribute__((ext_vector_type(8)));
typedef _Float16 f16x8 __attribute__((ext_vector_type(8)));
typedef float f32x4 __attribute__((ext_vector_type(4)));
typedef float f32x16 __attribute__((ext_vector_type(16)));
typedef unsigned int u32x4 __attribute__((ext_vector_type(4)));
typedef unsigned short u16;

__device__ __forceinline__ float bf2f(u16 u) {
    return __builtin_bit_cast(float, ((unsigned)u) << 16);
}
__device__ __forceinline__ u16 f2bf(float f) {
    unsigned u = __builtin_bit_cast(unsigned, f);
    unsigned r = 0x7FFFu + ((u >> 16) & 1u);
    return (u16)((u + r) >> 16);
}
__device__ __forceinline__ u16 f2h(float f) {
    _Float16 h = (_Float16)f;
    return __builtin_bit_cast(u16, h);
}
__device__ __forceinline__ bf16x8 ldfrag(const u16* p) {
    return __builtin_bit_cast(bf16x8, *(const uint4*)p);
}
__device__ __forceinline__ f16x8 ldfragh(const u16* p) {
    return __builtin_bit_cast(f16x8, *(const uint4*)p);
}
__device__ __forceinline__ f32x4 mfma16h(f16x8 a, f16x8 b, f32x4 c) {
    return __builtin_amdgcn_mfma_f32_16x16x32_f16(a, b, c, 0, 0, 0);
}
__device__ __forceinline__ f32x4 mfma16b(bf16x8 a, bf16x8 b, f32x4 c) {
    return __builtin_amdgcn_mfma_f32_16x16x32_bf16(a, b, c, 0, 0, 0);
}
__device__ __forceinline__ f32x16 mfma32(bf16x8 a, bf16x8 b, f32x16 c) {
    return __builtin_amdgcn_mfma_f32_32x32x16_bf16(a, b, c, 0, 0, 0);
}
__device__ __forceinline__ f32x16 mfma32h(f16x8 a, f16x8 b, f32x16 c) {
    return __builtin_amdgcn_mfma_f32_32x32x16_f16(a, b, c, 0, 0, 0);
}
// pack two f32 -> one u32 of 2x bf16 (lo=a, hi=b); no builtin on gfx950 (T12 recipe)
__device__ __forceinline__ unsigned cvt_pk_bf16(float a, float b) {
    unsigned r;
    asm("v_cvt_pk_bf16_f32 %0, %1, %2" : "=v"(r) : "v"(a), "v"(b));
    return r;
}
// async global->LDS, 16B/lane; LDS dest = wave-uniform base + lane*16 (m97 contract)
__device__ __forceinline__ void gl2lds16(const u16* g, u16* l) {
    __builtin_amdgcn_global_load_lds(
        (const __attribute__((address_space(1))) u16*)g,
        (__attribute__((address_space(3))) u16*)l, 16, 0, 0);
}

// ---------------- fused prologue: mask, bias, transpose Wq/Wk/Wv, convert X ----------------
// blk 0 = mask (single block, starts FIRST so its serial tail overlaps the convert wave)
// blk 1..12 = bias concat; blk 13..3084 = W transposes; blk 3085..11276 = X convert.
__global__ __launch_bounds__(256) void prologue(
    const float* __restrict__ X, u16* __restrict__ Xh,
    const float* __restrict__ Wq, const float* __restrict__ Wk, const float* __restrict__ Wv,
    u16* __restrict__ Wqt, u16* __restrict__ Wkt, u16* __restrict__ Wvt,
    const float* __restrict__ bq, const float* __restrict__ bk, const float* __restrict__ bv,
    float* __restrict__ bcat,
    const unsigned char* __restrict__ mraw, float* __restrict__ mnorm, float* __restrict__ cntp)
{
    __shared__ float tl[32][33];
    __shared__ int flags;
    __shared__ float scnt[Bb];
    const int blk = blockIdx.x, tid = threadIdx.x;

    if (blk == 0) {                                 // mask normalization + per-batch count
        const int n = Bb * Ss;
        if (tid == 0) flags = 0;
        if (tid < Bb) scnt[tid] = 0.f;
        __syncthreads();
        int f = 0;
        for (int i = tid; i < n; i += 256) {
            unsigned char c = mraw[i];
            if ((i & 3) != 0 && c) f |= 1;
            if ((i & 3) == 1 && c >= 2) f |= 2;
            if ((i & 3) == 3 && c >= 2) f |= 4;
        }
        if (f) atomicOr(&flags, f);
        __syncthreads();
        int fl = flags;
        int layout;                                 // 0=int32, 1=u8, 2=bf16, 3=f32
        if (!(fl & 1)) layout = 0;
        else if (fl & 2) layout = 2;
        else if (fl & 4) layout = 3;
        else layout = 1;
        for (int i = tid; i < n; i += 256) {
            int v;
            if (layout == 0)      v = ((const int*)mraw)[i];
            else if (layout == 1) v = mraw[i];
            else if (layout == 2) v = ((const u16*)mraw)[i] != 0;
            else                  v = ((const unsigned*)mraw)[i] != 0;
            mnorm[i] = (v != 0) ? 1.0f : 0.0f;
            if (v == 0) atomicAdd(&scnt[i >> 11], 1.0f);
        }
        __syncthreads();
        if (tid < Bb) cntp[tid] = scnt[tid];
    } else if (blk < 13) {                          // bias concat
        int i = (blk - 1) * 256 + tid;
        bcat[i] = (i < 1024) ? bq[i] : ((i < 2048) ? bk[i - 1024] : bv[i - 2048]);
    } else if (blk < 3085) {                        // W transpose fp32 -> fp16 (3 weights)
        int idx = blk - 13;
        int w = idx >> 10, t = idx & 1023;
        const float* W = (w == 0) ? Wq : ((w == 1) ? Wk : Wv);
        u16* Wt = (w == 0) ? Wqt : ((w == 1) ? Wkt : Wvt);
        const int tx = tid & 31, ty = tid >> 5;     // 32 x 8
        const int n0 = (t & 31) * 32, k0 = (t >> 5) * 32;
        #pragma unroll
        for (int i = 0; i < 4; i++)
            tl[ty + i * 8][tx] = W[(size_t)(k0 + ty + i * 8) * Dd + n0 + tx];
        __syncthreads();
        #pragma unroll
        for (int i = 0; i < 4; i++)
            Wt[(size_t)(n0 + ty + i * 8) * Dd + k0 + tx] = f2h(tl[tx][ty + i * 8]);
    } else {                                        // X fp32 -> fp16
        size_t i = ((size_t)(blk - 3085) * 256 + tid) * 4;
        float4 v = *(const float4*)(X + i);
        u16 h0 = f2h(v.x), h1 = f2h(v.y), h2 = f2h(v.z), h3 = f2h(v.w);
        uint2 ph = { (unsigned)h0 | ((unsigned)h1 << 16), (unsigned)h2 | ((unsigned)h3 << 16) };
        *(uint2*)(Xh + i) = ph;
    }
}

// ---------------- fused QKV GEMM (fp16, pipelined 256x128, mfma 16x16x32) ----------------
__global__ __launch_bounds__(512, 2) void gemm_qkv(
    const u16* __restrict__ Ah, const u16* __restrict__ Wcat, const float* __restrict__ bcat,
    const float* __restrict__ mnorm,
    u16* __restrict__ Qb, u16* __restrict__ Kb, u16* __restrict__ Vt)
{
    __shared__ u16 As[3][256][64];   // 96 KiB, triple-buffered
    __shared__ u16 Bs[2][128][64];   // 32 KiB, double-buffered
    const int tid = threadIdx.x, lane = tid & 63, wave = tid >> 6;
    const int wm = wave >> 1, wn = wave & 1;
    const int bm = blockIdx.y * 256, bn = blockIdx.x * 128;
    const bool isQ = (bn < 1024);
    const int l15 = lane & 15, lq = lane >> 4;
    const int rl = lane >> 3;                       // row-in-chunk 0..7
    const int s8 = ((lane & 7) ^ rl) * 8;           // T2 pre-swizzled source slot (u16 units)
    const u16* agp = Ah + (size_t)(bm + wave * 32 + rl) * Dd + s8;
    const u16* bgp = Wcat + (size_t)(bn + wave * 16 + rl) * Dd + s8;

    f32x4 acc[4][4] = {};

    auto stageA = [&](int slot, int kt) {
        u16* d = &As[slot][wave * 32][0];           // wave-uniform dest
        const u16* g = agp + kt * 64;
        #pragma unroll
        for (int j = 0; j < 4; ++j)
            gl2lds16(g + (size_t)(j * 8) * Dd, d + j * 8 * 64);
    };
    auto stageB = [&](int slot, int kt) {
        u16* d = &Bs[slot][wave * 16][0];
        const u16* g = bgp + kt * 64;
        #pragma unroll
        for (int j = 0; j < 2; ++j)
            gl2lds16(g + (size_t)(j * 8) * Dd, d + j * 8 * 64);
    };

    // prologue: A0(4), B0(2), A1(4) -> wait until only A1 outstanding
    stageA(0, 0); stageB(0, 0); stageA(1, 1);
    asm volatile("s_waitcnt vmcnt(4)" ::: "memory");
    __builtin_amdgcn_s_barrier();

    int cs = 0;                                     // compute slot for A
    for (int t = 0; t < 16; ++t) {
        if (t < 15) stageB((t + 1) & 1, t + 1);
        if (t < 14) { int ss = (cs >= 1) ? cs - 1 : cs + 2; stageA(ss, t + 2); }
        #pragma unroll
        for (int kf = 0; kf < 2; kf++) {
            f16x8 b[4], a[4];
            #pragma unroll
            for (int nt = 0; nt < 4; nt++)
                b[nt] = ldfragh(&Bs[t & 1][wn * 64 + nt * 16 + l15][(kf * 32 + lq * 8) ^ ((l15 & 7) * 8)]);
            #pragma unroll
            for (int mt = 0; mt < 4; mt++)
                a[mt] = ldfragh(&As[cs][wm * 64 + mt * 16 + l15][(kf * 32 + lq * 8) ^ ((l15 & 7) * 8)]);
            #pragma unroll
            for (int mt = 0; mt < 4; mt++)
                #pragma unroll
                for (int nt = 0; nt < 4; nt++)
                    acc[mt][nt] = mfma16h(a[mt], b[nt], acc[mt][nt]);
        }
        // counted drain: oldest {A(t+1), B(t+1)} done; {A(t+2)} stays in flight
        if (t < 14)       asm volatile("s_waitcnt vmcnt(4)" ::: "memory");
        else if (t == 14) asm volatile("s_waitcnt vmcnt(0)" ::: "memory");
        if (t < 15) __builtin_amdgcn_s_barrier();
        cs = (cs >= 2) ? 0 : cs + 1;
    }

    const float LOG2E = 1.44269504088896f;
    float bv[4];
    #pragma unroll
    for (int nt = 0; nt < 4; nt++) bv[nt] = bcat[bn + wn * 64 + nt * 16 + l15];
    #pragma unroll
    for (int mt = 0; mt < 4; mt++) {
        int r0 = bm + wm * 64 + mt * 16 + lq * 4;
        float mk[4];
        if (!isQ) {
            #pragma unroll
            for (int rr = 0; rr < 4; rr++) mk[rr] = mnorm[r0 + rr];
        }
        #pragma unroll
        for (int nt = 0; nt < 4; nt++) {
            int col = bn + wn * 64 + nt * 16 + l15;
            if (col < 1024) {                                  // Q fp16 (pre-scaled by log2e)
                #pragma unroll
                for (int rr = 0; rr < 4; rr++)
                    Qb[(size_t)(r0 + rr) * Dd + col] = f2h((acc[mt][nt][rr] + bv[nt]) * LOG2E);
            } else if (col < 2048) {                           // K fp16 (masked rows -> 0)
                int c2 = col - 1024;
                #pragma unroll
                for (int rr = 0; rr < 4; rr++)
                    Kb[(size_t)(r0 + rr) * Dd + c2] = f2h((acc[mt][nt][rr] + bv[nt]) * mk[rr]);
            } else {                                           // V bf16, transposed [b][h][d][s], masked
                int c2 = col - 2048;
                int hh = c2 >> 6, dd = c2 & 63, b_ = r0 >> 11, s0 = r0 & 2047;
                u16 e0 = f2bf((acc[mt][nt][0] + bv[nt]) * mk[0]);
                u16 e1 = f2bf((acc[mt][nt][1] + bv[nt]) * mk[1]);
                u16 e2 = f2bf((acc[mt][nt][2] + bv[nt]) * mk[2]);
                u16 e3 = f2bf((acc[mt][nt][3] + bv[nt]) * mk[3]);
                uint2 pk = { (unsigned)e0 | ((unsigned)e1 << 16), (unsigned)e2 | ((unsigned)e3 << 16) };
                *(uint2*)(Vt + (size_t)((b_ * Hh + hh) * 64 + dd) * Ss + s0) = pk;
            }
        }
    }
}

// ---------------- output projection (bf16, pipelined 256x128): fp32 out ----------------
__global__ __launch_bounds__(512, 2) void gemm_out(
    const u16* __restrict__ Ah, const u16* __restrict__ Wt,
    const float* __restrict__ bias, float* __restrict__ Cout)
{
    __shared__ u16 As[3][256][64];
    __shared__ u16 Bs[2][128][64];
    const int tid = threadIdx.x, lane = tid & 63, wave = tid >> 6;
    const int wm = wave >> 1, wn = wave & 1;
    const int bm = blockIdx.y * 256, bn = blockIdx.x * 128;
    const int l15 = lane & 15, lq = lane >> 4;
    const int rl = lane >> 3;
    const int s8 = ((lane & 7) ^ rl) * 8;
    const u16* agp = Ah + (size_t)(bm + wave * 32 + rl) * Dd + s8;
    const u16* bgp = Wt + (size_t)(bn + wave * 16 + rl) * Dd + s8;

    f32x4 acc[4][4] = {};

    auto stageA = [&](int slot, int kt) {
        u16* d = &As[slot][wave * 32][0];
        const u16* g = agp + kt * 64;
        #pragma unroll
        for (int j = 0; j < 4; ++j)
            gl2lds16(g + (size_t)(j * 8) * Dd, d + j * 8 * 64);
    };
    auto stageB = [&](int slot, int kt) {
        u16* d = &Bs[slot][wave * 16][0];
        const u16* g = bgp + kt * 64;
        #pragma unroll
        for (int j = 0; j < 2; ++j)
            gl2lds16(g + (size_t)(j * 8) * Dd, d + j * 8 * 64);
    };

    stageA(0, 0); stageB(0, 0); stageA(1, 1);
    asm volatile("s_waitcnt vmcnt(4)" ::: "memory");
    __builtin_amdgcn_s_barrier();

    int cs = 0;
    for (int t = 0; t < 16; ++t) {
        if (t < 15) stageB((t + 1) & 1, t + 1);
        if (t < 14) { int ss = (cs >= 1) ? cs - 1 : cs + 2; stageA(ss, t + 2); }
        #pragma unroll
        for (int kf = 0; kf < 2; kf++) {
            bf16x8 b[4], a[4];
            #pragma unroll
            for (int nt = 0; nt < 4; nt++)
                b[nt] = ldfrag(&Bs[t & 1][wn * 64 + nt * 16 + l15][(kf * 32 + lq * 8) ^ ((l15 & 7) * 8)]);
            #pragma unroll
            for (int mt = 0; mt < 4; mt++)
                a[mt] = ldfrag(&As[cs][wm * 64 + mt * 16 + l15][(kf * 32 + lq * 8) ^ ((l15 & 7) * 8)]);
            #pragma unroll
            for (int mt = 0; mt < 4; mt++)
                #pragma unroll
                for (int nt = 0; nt < 4; nt++)
                    acc[mt][nt] = mfma16b(a[mt], b[nt], acc[mt][nt]);
        }
        if (t < 14)       asm volatile("s_waitcnt vmcnt(4)" ::: "memory");
        else if (t == 14) asm volatile("s_waitcnt vmcnt(0)" ::: "memory");
        if (t < 15) __builtin_amdgcn_s_barrier();
        cs = (cs >= 2) ? 0 : cs + 1;
    }

    float bv[4];
    #pragma unroll
    for (int nt = 0; nt < 4; nt++) bv[nt] = bias[bn + wn * 64 + nt * 16 + l15];
    #pragma unroll
    for (int mt = 0; mt < 4; mt++) {
        int r0 = bm + wm * 64 + mt * 16 + lq * 4;
        #pragma unroll
        for (int nt = 0; nt < 4; nt++) {
            int col = bn + wn * 64 + nt * 16 + l15;
            #pragma unroll
            for (int rr = 0; rr < 4; rr++)
                Cout[(size_t)(r0 + rr) * Dd + col] = acc[mt][nt][rr] + bv[nt];
        }
    }
}

// ---------------- MFMA flash attention v8b: KVBLK=128, T12, setprio, + fused Wo transpose -------
// grid (72, 8): x<64 -> attention (bh = x); x>=64 -> Wo transpose (64 blocks, 16 tiles each).
// 72 % 8 == 0 keeps same-head q-tile blocks on one XCD (K/V L2 locality — r20 lesson).
__global__ __launch_bounds__(512, 4) void attn_mfma(
    u16* qctx, const u16* __restrict__ Kb, const u16* __restrict__ Vt,
    const float* __restrict__ maskf, const float* __restrict__ cntp,
    const float* __restrict__ Wo, u16* __restrict__ Wot)
{
    __shared__ u16 Ks[128][72];      // [key][d] fp16  (144B rows)
    __shared__ u16 Vs[64][136];      // [d][key] bf16  (272B rows)
    __shared__ float li_s[8][32];    // per-wave li broadcast (epilogue only)
    const int tid = threadIdx.x, lane = tid & 63, wave = tid >> 6;

    if (blockIdx.x >= 64) {
        // ---- Wo [K][N] fp32 -> Wot [N][K] bf16; LDS overlaid on Ks (>= 2x32x33x4 B) ----
        float* tlb = (float*)&Ks[0][0];
        const int idx = (blockIdx.x - 64) * 8 + blockIdx.y;   // 0..63
        const int sub = tid >> 8;                   // 0..1 (two tiles in parallel)
        const int st = tid & 255;
        const int tx = st & 31, ty = st >> 5;       // 32 x 8
        float* tl = tlb + sub * 32 * 33;
        #pragma unroll 1
        for (int it = 0; it < 8; ++it) {
            int t = idx * 16 + it * 2 + sub;
            int n0 = (t & 31) * 32, k0 = (t >> 5) * 32;
            #pragma unroll
            for (int i = 0; i < 4; i++)
                tl[(ty + i * 8) * 33 + tx] = Wo[(size_t)(k0 + ty + i * 8) * Dd + n0 + tx];
            __syncthreads();
            #pragma unroll
            for (int i = 0; i < 4; i++)
                Wot[(size_t)(n0 + ty + i * 8) * Dd + k0 + tx] = f2bf(tl[tx * 33 + ty + i * 8]);
            __syncthreads();
        }
        return;
    }

    const int l31 = lane & 31, hi = lane >> 5;
    const int bh = blockIdx.x, h = bh & 15, b = bh >> 4;
    const int q0 = blockIdx.y * 256;

    f16x8 qa[4];
    {
        const u16* qp = qctx + (size_t)(b * Ss + q0 + wave * 32 + l31) * Dd + h * 64 + hi * 8;
        #pragma unroll
        for (int kf = 0; kf < 4; kf++) qa[kf] = ldfragh(qp + kf * 16);
    }

    // K staging: rows kr, kr+64 (keys within tile); V staging: d rows vd, vd+32
    const int kr = tid >> 3, kc = (tid & 7) * 8;
    const int vd = tid >> 4, vc = (tid & 15) * 8;
    const u16* kgb = Kb + ((size_t)b * Ss + kr) * Dd + h * 64 + kc;
    const u16* vgb = Vt + (((size_t)(b * Hh + h)) * 64 + vd) * Ss + vc;

    f32x16 acc0 = {}, acc1 = {};
    float li = 0.f;

    uint4 kreg0 = *(const uint4*)(kgb);
    uint4 kreg1 = *(const uint4*)(kgb + (size_t)64 * Dd);
    uint4 vreg0 = *(const uint4*)(vgb);
    uint4 vreg1 = *(const uint4*)(vgb + (size_t)32 * Ss);

    for (int k0 = 0; k0 < Ss; k0 += 128) {
        __syncthreads();
        *(uint4*)&Ks[kr][kc]      = kreg0;
        *(uint4*)&Ks[kr + 64][kc] = kreg1;
        *(uint4*)&Vs[vd][vc]      = vreg0;
        *(uint4*)&Vs[vd + 32][vc] = vreg1;
        __syncthreads();
        int k0n = (k0 + 128 < Ss) ? k0 + 128 : 0;
        kreg0 = *(const uint4*)(kgb + (size_t)k0n * Dd);
        kreg1 = *(const uint4*)(kgb + (size_t)(k0n + 64) * Dd);
        vreg0 = *(const uint4*)(vgb + k0n);
        vreg1 = *(const uint4*)(vgb + (size_t)32 * Ss + k0n);

        #pragma unroll
        for (int nt = 0; nt < 4; nt++) {
            // QK^T swapped: A=K rows (32 keys), B=Q cols (32 q). Lane: q=l31, key=crow(r,hi).
            f32x16 sc = {};
            __builtin_amdgcn_s_setprio(1);
            #pragma unroll
            for (int kf = 0; kf < 4; kf++) {
                f16x8 kb = ldfragh(&Ks[nt * 32 + l31][kf * 16 + hi * 8]);
                sc = mfma32h(kb, qa[kf], sc);
            }
            __builtin_amdgcn_s_setprio(0);
            float p[16];
            #pragma unroll
            for (int r = 0; r < 8; r++) p[r] = __builtin_amdgcn_exp2f(sc[r]);
            li += ((p[0] + p[1]) + (p[2] + p[3])) + ((p[4] + p[5]) + (p[6] + p[7]));
            {
                unsigned w0 = cvt_pk_bf16(p[0], p[1]), w1 = cvt_pk_bf16(p[2], p[3]);
                unsigned w2 = cvt_pk_bf16(p[4], p[5]), w3 = cvt_pk_bf16(p[6], p[7]);
                auto s02 = __builtin_amdgcn_permlane32_swap((int)w0, (int)w2, false, false);
                auto s13 = __builtin_amdgcn_permlane32_swap((int)w1, (int)w3, false, false);
                u32x4 pw = { (unsigned)s02[0], (unsigned)s13[0], (unsigned)s02[1], (unsigned)s13[1] };
                bf16x8 pa0 = __builtin_bit_cast(bf16x8, pw);
                bf16x8 v00 = ldfrag(&Vs[l31][nt * 32 + hi * 8]);
                bf16x8 v10 = ldfrag(&Vs[32 + l31][nt * 32 + hi * 8]);
                __builtin_amdgcn_s_setprio(1);
                acc0 = mfma32(pa0, v00, acc0);
                acc1 = mfma32(pa0, v10, acc1);
                __builtin_amdgcn_s_setprio(0);
            }
            #pragma unroll
            for (int r = 8; r < 16; r++) p[r] = __builtin_amdgcn_exp2f(sc[r]);
            li += ((p[8] + p[9]) + (p[10] + p[11])) + ((p[12] + p[13]) + (p[14] + p[15]));
            {
                unsigned w4 = cvt_pk_bf16(p[8], p[9]),  w5 = cvt_pk_bf16(p[10], p[11]);
                unsigned w6 = cvt_pk_bf16(p[12], p[13]), w7 = cvt_pk_bf16(p[14], p[15]);
                auto s46 = __builtin_amdgcn_permlane32_swap((int)w4, (int)w6, false, false);
                auto s57 = __builtin_amdgcn_permlane32_swap((int)w5, (int)w7, false, false);
                u32x4 pw = { (unsigned)s46[0], (unsigned)s57[0], (unsigned)s46[1], (unsigned)s57[1] };
                bf16x8 pa1 = __builtin_bit_cast(bf16x8, pw);
                bf16x8 v01 = ldfrag(&Vs[l31][nt * 32 + 16 + hi * 8]);
                bf16x8 v11 = ldfrag(&Vs[32 + l31][nt * 32 + 16 + hi * 8]);
                __builtin_amdgcn_s_setprio(1);
                acc0 = mfma32(pa1, v01, acc0);
                acc1 = mfma32(pa1, v11, acc1);
                __builtin_amdgcn_s_setprio(0);
            }
        }
    }

    float li_tot = li + __shfl_xor(li, 32);
    if (hi == 0) li_s[wave][l31] = li_tot;
    __builtin_amdgcn_s_barrier();
    float cntb = cntp[b];
    #pragma unroll
    for (int g = 0; g < 4; g++) {
        float4 lv = *(const float4*)&li_s[wave][g * 8 + hi * 4];
        #pragma unroll
        for (int j = 0; j < 4; j++) {
            int r = g * 4 + j;
            int row = j + 8 * g + 4 * hi;
            int q = q0 + wave * 32 + row;
            float qm = maskf[b * Ss + q];
            float den = lv[j] - cntb;
            float rl = den > 0.f ? qm / den : 0.f;
            u16* op = qctx + (size_t)(b * Ss + q) * Dd + h * 64 + l31;
            op[0]  = f2bf(acc0[r] * rl);
            op[32] = f2bf(acc1[r] * rl);
        }
    }
}

extern "C" void kernel_launch(void* const* d_in, const int* in_sizes, int n_in,
                              void* d_out, int out_size, void* d_ws, size_t ws_size,
                              hipStream_t stream) {
    const float* X  = (const float*)d_in[0];
    const unsigned char* mr = (const unsigned char*)d_in[1];
    const float* Wq = (const float*)d_in[2];
    const float* bq = (const float*)d_in[3];
    const float* Wk = (const float*)d_in[4];
    const float* bk = (const float*)d_in[5];
    const float* Wv = (const float*)d_in[6];
    const float* bv = (const float*)d_in[7];
    const float* Wo = (const float*)d_in[8];
    const float* bo = (const float*)d_in[9];
    float* out = (float*)d_out;

    // ws (64 MB)
    u16* wsb = (u16*)d_ws;
    u16* Xh  = wsb;                // fp16 X; dies after QKV-gemm; Wo^T overlays
    u16* Qb  = wsb + (size_t)SZt;  // fp16 Q; ctx (bf16) aliases after attention
    u16* Kb  = wsb + 2 * (size_t)SZt;   // fp16 K
    u16* Vt  = wsb + 3 * (size_t)SZt;   // bf16 V^T
    u16* Wot = Xh;
    // d_out scratch (all dead before gemm_out writes d_out)
    u16* ob  = (u16*)d_out;
    u16* Wcat = ob + (size_t)SZt;              // fp16 Wqt|Wkt|Wvt contiguous = [3072][1024]
    u16* Wqt = Wcat;
    u16* Wkt = Wqt + 1048576;
    u16* Wvt = Wkt + 1048576;
    float* mnorm = (float*)(Wvt + 1048576);    // 32 KB
    float* bcat  = mnorm + Bb * Ss;            // 12 KB
    float* cntp  = bcat + 3072;                // 16 B (per-batch masked-key count)

    prologue<<<11277, 256, 0, stream>>>(X, Xh, Wq, Wk, Wv, Wqt, Wkt, Wvt,
                                        bq, bk, bv, bcat, mr, mnorm, cntp);
    gemm_qkv<<<dim3(24, 32), 512, 0, stream>>>(Xh, Wcat, bcat, mnorm, Qb, Kb, Vt);
    attn_mfma<<<dim3(72, Ss / 256), 512, 0, stream>>>(Qb, Kb, Vt, mnorm, cntp, Wo, Wot);
    gemm_out<<<dim3(8, 32), 512, 0, stream>>>(Qb, Wot, bo, out);
}